// Round 4
// baseline (394.171 us; speedup 1.0000x reference)
//
#include <hip/hip_runtime.h>

#define QLEN 1024
#define PASTN 3072
#define KVLEN 4096
#define HIDN 4096
#define NHEAD 32
#define NKVH 8
#define HDIM 128
#define NQKVC 6144  // 4096 (Wq) + 1024 (Wk) + 1024 (Wv)

typedef unsigned short u16;
typedef __bf16 bf16x8 __attribute__((ext_vector_type(8)));
typedef float f32x4 __attribute__((ext_vector_type(4)));
typedef float f32x16 __attribute__((ext_vector_type(16)));
typedef u16 us8 __attribute__((ext_vector_type(8)));
typedef u16 us4 __attribute__((ext_vector_type(4)));

__device__ __forceinline__ u16 f2bf(float x) {
  unsigned u = __builtin_bit_cast(unsigned, x);
  u += 0x7fffu + ((u >> 16) & 1u);
  return (u16)(u >> 16);
}
__device__ __forceinline__ float bf2f(u16 b) {
  return __builtin_bit_cast(float, (unsigned)b << 16);
}

// async global->LDS, 16B per lane; LDS dest is wave-uniform base (+lane*16)
#define GLL16(gp, lp) __builtin_amdgcn_global_load_lds( \
    (const __attribute__((address_space(1))) void*)(gp), \
    (__attribute__((address_space(3))) void*)(lp), 16, 0, 0)

// ---------------------------------------------------------------- convert
__global__ __launch_bounds__(256) void cvt_kernel(const float* __restrict__ src,
                                                  u16* __restrict__ dst, int n) {
  int i = (blockIdx.x * 256 + threadIdx.x) * 4;
  if (i >= n) return;
  float4 f = *(const float4*)(src + i);
  ushort4 o = make_ushort4(f2bf(f.x), f2bf(f.y), f2bf(f.z), f2bf(f.w));
  *(ushort4*)(dst + i) = o;
}

// ---------------------------------------------------------------- GEMM C = A * B^T
__device__ __forceinline__ void storeC(float* p, float v) { *p = v; }
__device__ __forceinline__ void storeC(u16* p, float v) { *p = f2bf(v); }

template <typename CT>
__global__ __launch_bounds__(256) void gemm_bt(const u16* __restrict__ A,
                                               const u16* __restrict__ B,
                                               CT* __restrict__ C, int M, int N, int K) {
  __shared__ u16 Alds[2][128 * 32];
  __shared__ u16 Blds[2][128 * 32];
  const int tid = threadIdx.x, wid = tid >> 6, lane = tid & 63;
  const int m0 = blockIdx.y * 128, n0 = blockIdx.x * 128;
  const int wm = (wid >> 1) * 64, wn = (wid & 1) * 64;
  const int l15 = lane & 15, l4 = lane >> 4;
  const int srow = lane >> 2, scol = (lane & 3) * 8;
  f32x4 acc[4][4] = {};
  auto stage = [&](int buf, int kt) {
#pragma unroll
    for (int i = 0; i < 2; ++i) {
      int c = wid * 2 + i;
      GLL16(A + (size_t)(m0 + c * 16 + srow) * K + kt + scol, &Alds[buf][c * 512]);
      GLL16(B + (size_t)(n0 + c * 16 + srow) * K + kt + scol, &Blds[buf][c * 512]);
    }
  };
  stage(0, 0);
  __syncthreads();
  int cur = 0;
  for (int kt = 0; kt < K; kt += 32) {
    if (kt + 32 < K) stage(cur ^ 1, kt + 32);
    bf16x8 a[4], b[4];
#pragma unroll
    for (int i = 0; i < 4; ++i) {
      a[i] = *(const bf16x8*)&Alds[cur][(wm + i * 16 + l15) * 32 + l4 * 8];
      b[i] = *(const bf16x8*)&Blds[cur][(wn + i * 16 + l15) * 32 + l4 * 8];
    }
#pragma unroll
    for (int i = 0; i < 4; ++i)
#pragma unroll
      for (int j = 0; j < 4; ++j)
        acc[i][j] = __builtin_amdgcn_mfma_f32_16x16x32_bf16(a[i], b[j], acc[i][j], 0, 0, 0);
    __syncthreads();
    cur ^= 1;
  }
#pragma unroll
  for (int i = 0; i < 4; ++i)
#pragma unroll
    for (int j = 0; j < 4; ++j) {
      int row = m0 + wm + i * 16 + l4 * 4;
      int col = n0 + wn + j * 16 + l15;
#pragma unroll
      for (int r = 0; r < 4; ++r) storeC(&C[(size_t)(row + r) * N + col], acc[i][j][r]);
    }
}

// ---------------------------------------------------------------- RoPE on Q
__global__ __launch_bounds__(256) void rope_q_kernel(const u16* __restrict__ qkv,
                                                     u16* __restrict__ qr) {
  int idx = blockIdx.x * 256 + threadIdx.x;  // 1024*32*64
  int i = idx & 63, h = (idx >> 6) & 31, r = idx >> 11;
  float freq = __expf(-(float)i * (9.210340371976184f / 64.f));
  float angle = (float)(PASTN + r) * freq;
  float sn, cs;
  sincosf(angle, &sn, &cs);
  int base = r * NQKVC + h * HDIM + i;
  float x1 = bf2f(qkv[base]);
  float x2 = bf2f(qkv[base + 64]);
  int ob = r * HIDN + h * HDIM + i;
  qr[ob] = f2bf(x1 * cs - x2 * sn);
  qr[ob + 64] = f2bf(x2 * cs + x1 * sn);
}

// ---------------------------------------------------------------- K cache build
__global__ __launch_bounds__(256) void repack_k_kernel(const float* __restrict__ past_k,
                                                       const u16* __restrict__ qkv,
                                                       u16* __restrict__ kb) {
  int idx = blockIdx.x * 256 + threadIdx.x;  // 8*4096*128
  int d = idx & 127, kv = (idx >> 7) & 4095, hk = idx >> 19;
  float val;
  if (kv < PASTN) {
    val = past_k[((size_t)hk * PASTN + kv) * HDIM + d];
  } else {
    int r = kv - PASTN;
    float x = bf2f(qkv[(size_t)r * NQKVC + 4096 + hk * HDIM + d]);
    float xp = bf2f(qkv[(size_t)r * NQKVC + 4096 + hk * HDIM + (d ^ 64)]);
    int i = d & 63;
    float freq = __expf(-(float)i * (9.210340371976184f / 64.f));
    float angle = (float)(PASTN + r) * freq;
    float sn, cs;
    sincosf(angle, &sn, &cs);
    val = (d < 64) ? (x * cs - xp * sn) : (x * cs + xp * sn);
  }
  kb[idx] = f2bf(val);
}

// ---------------------------------------------------------------- V^T cache build
__global__ __launch_bounds__(256) void repack_vt_kernel(const float* __restrict__ past_v,
                                                        const u16* __restrict__ qkv,
                                                        u16* __restrict__ vtb) {
  __shared__ u16 tile[32][136];
  int hk = blockIdx.y, kv0 = blockIdx.x * 32, tid = threadIdx.x;
  int j = tid >> 3, d0 = (tid & 7) * 16;
  if (kv0 < PASTN) {
    const float* src = past_v + ((size_t)hk * PASTN + kv0 + j) * HDIM + d0;
#pragma unroll
    for (int x = 0; x < 16; x += 4) {
      float4 f = *(const float4*)(src + x);
      tile[j][d0 + x] = f2bf(f.x);
      tile[j][d0 + x + 1] = f2bf(f.y);
      tile[j][d0 + x + 2] = f2bf(f.z);
      tile[j][d0 + x + 3] = f2bf(f.w);
    }
  } else {
    int r = kv0 - PASTN + j;
    const u16* src = qkv + (size_t)r * NQKVC + 5120 + hk * HDIM + d0;
    *(us8*)&tile[j][d0] = *(const us8*)src;
    *(us8*)&tile[j][d0 + 8] = *(const us8*)(src + 8);
  }
  __syncthreads();
  int d = tid >> 1, jb = (tid & 1) * 16;
  us8 o0, o1;
#pragma unroll
  for (int x = 0; x < 8; ++x) {
    o0[x] = tile[jb + x][d];
    o1[x] = tile[jb + 8 + x][d];
  }
  u16* dst = vtb + ((size_t)hk * HDIM + d) * KVLEN + kv0 + jb;
  *(us8*)dst = o0;
  *(us8*)(dst + 8) = o1;
}

// ---------------------------------------------------------------- flash attention
// 32x32x16 MFMA, swapped operands: S^T = mfma(K, Q), q = lane&31 (wave = 32 q).
// K physical row p holds key kv0 + pi(p), pi = swap bits 2<->3; then the S^T
// registers are EXACTLY the PV B-fragment: pa[j] = s[t][8c'+j], no exchange.
// Lane's key for s[t][reg] = kv0 + 32t + (reg&7) + 8*hi + ((reg&8)<<1).
// K LDS 16-slot XOR swizzle (slot^row&15), V 8-slot (slot^d&7): 2-way = free.
__global__ __launch_bounds__(128) void attn_kernel(const u16* __restrict__ q,
                                                   const u16* __restrict__ kc,
                                                   const u16* __restrict__ vt,
                                                   u16* __restrict__ o) {
  __shared__ u16 Klds[2][64 * 128];  // [row][d], swizzled, rows permuted by pi
  __shared__ u16 Vlds[2][128 * 64];  // [d][kv], swizzled
  const int tid = threadIdx.x, wid = tid >> 6, lane = tid & 63;
  const int l31 = lane & 31, hi = lane >> 5, l15 = lane & 15;
  const int h = blockIdx.y, hk = h >> 2;
  const int q0 = blockIdx.x * 64;
  const int qrow = q0 + wid * 32 + l31;
  // Q B-frag: qf[dk] = Q[qrow][dk*16 + hi*8 + 0..7]
  bf16x8 qf[8];
  {
    const u16* qp = q + (size_t)qrow * HIDN + h * HDIM + hi * 8;
#pragma unroll
    for (int dk = 0; dk < 8; ++dk) qf[dk] = *(const bf16x8*)(qp + dk * 16);
  }
  float m_run = -1e30f, l_run = 0.f;
  f32x16 oacc[4] = {};
  const u16* kbase = kc + (size_t)hk * KVLEN * HDIM;
  const u16* vbase = vt + (size_t)hk * HDIM * KVLEN;
  const int ntiles = (PASTN + q0 + 64) >> 6;
  const float C = 0.12753102f;  // log2(e)/sqrt(128)
  const int qpos = PASTN + qrow;
  auto stage = [&](int buf, int kv0) {
    // K: 8 insts/wave, inst covers 4 physical rows (1KB)
#pragma unroll
    for (int i = 0; i < 8; ++i) {
      const int w = wid * 8 + i;
      const int p = w * 4 + (lane >> 4);
      const int key = (p & 0x33) | ((p & 4) << 1) | ((p & 8) >> 1);
      const int sl = (lane & 15) ^ (p & 15);
      GLL16(kbase + (size_t)(kv0 + key) * HDIM + sl * 8, &Klds[buf][w * 512]);
    }
    // V: 8 insts/wave, inst covers 8 d-rows (1KB)
#pragma unroll
    for (int i = 0; i < 8; ++i) {
      const int w = wid * 8 + i;
      const int d = w * 8 + (lane >> 3);
      const int sl = (lane & 7) ^ ((lane >> 3) & 7);
      GLL16(vbase + (size_t)d * KVLEN + kv0 + sl * 8, &Vlds[buf][w * 512]);
    }
  };
  stage(0, 0);
  __syncthreads();
  int cur = 0;
  for (int t = 0; t < ntiles; ++t) {
    if (t + 1 < ntiles) stage(cur ^ 1, (t + 1) << 6);
    const int kv0 = t << 6;
    const u16* Kb = Klds[cur];
    const u16* Vb = Vlds[cur];
    // QK^T: s[tt] = S^T over keys kv0+32tt.., accumulated over 8 dk chunks
    f32x16 s[2] = {};
    __builtin_amdgcn_s_setprio(1);
#pragma unroll
    for (int tt = 0; tt < 2; ++tt)
#pragma unroll
      for (int dk = 0; dk < 8; ++dk) {
        const int idx = (tt * 32 + l31) * 128 + (((dk * 2 + hi) ^ l15) * 8);
        bf16x8 kf = *(const bf16x8*)&Kb[idx];
        s[tt] = __builtin_amdgcn_mfma_f32_32x32x16_bf16(kf, qf[dk], s[tt], 0, 0, 0);
      }
    __builtin_amdgcn_s_setprio(0);
    // scale to log2 domain, mask (last tile only), in-lane max
    float pm = -1e30f;
    if (t == ntiles - 1) {
#pragma unroll
      for (int tt = 0; tt < 2; ++tt)
#pragma unroll
        for (int reg = 0; reg < 16; ++reg) {
          const int key = kv0 + tt * 32 + (reg & 7) + 8 * hi + ((reg & 8) << 1);
          float v = s[tt][reg] * C;
          if (key > qpos) v = -1e30f;
          s[tt][reg] = v;
          pm = fmaxf(pm, v);
        }
    } else {
#pragma unroll
      for (int tt = 0; tt < 2; ++tt)
#pragma unroll
        for (int reg = 0; reg < 16; ++reg) {
          float v = s[tt][reg] * C;
          s[tt][reg] = v;
          pm = fmaxf(pm, v);
        }
    }
    pm = fmaxf(pm, __shfl_xor(pm, 32));  // partner half holds the other keys
    // rescale only when the running max actually grows (skip-rescale)
    if (!__all(pm <= m_run)) {
      const float mn = fmaxf(m_run, pm);
      const float corr = exp2f(m_run - mn);
      m_run = mn;
      l_run *= corr;
#pragma unroll
      for (int db = 0; db < 4; ++db)
#pragma unroll
        for (int r = 0; r < 16; ++r) oacc[db][r] *= corr;
    }
    float rs = 0.f;
#pragma unroll
    for (int tt = 0; tt < 2; ++tt)
#pragma unroll
      for (int reg = 0; reg < 16; ++reg) {
        const float p = exp2f(s[tt][reg] - m_run);
        s[tt][reg] = p;
        rs += p;
      }
    rs += __shfl_xor(rs, 32);
    l_run += rs;
    // PV: O^T[d][q] += mfma(A=V^T frag, B=P). P B-frag = s[t][8c'..8c'+7].
    __builtin_amdgcn_s_setprio(1);
#pragma unroll
    for (int kc2 = 0; kc2 < 4; ++kc2) {
      bf16x8 pa;
#pragma unroll
      for (int j = 0; j < 8; ++j) pa[j] = (__bf16)s[kc2 >> 1][(kc2 & 1) * 8 + j];
#pragma unroll
      for (int db = 0; db < 4; ++db) {
        const int idx = (db * 32 + l31) * 64 + (((kc2 * 2 + hi) ^ (l31 & 7)) * 8);
        bf16x8 vf = *(const bf16x8*)&Vb[idx];
        oacc[db] = __builtin_amdgcn_mfma_f32_32x32x16_bf16(vf, pa, oacc[db], 0, 0, 0);
      }
    }
    __builtin_amdgcn_s_setprio(0);
    __syncthreads();
    cur ^= 1;
  }
  // epilogue: O^T regs (q=l31; d = db*32 + 8g + 4hi + j) -> swizzled LDS -> store
  const float inv = 1.f / l_run;
  u16* Olds = &Klds[0][0];
  const int orow = wid * 32 + l31;
#pragma unroll
  for (int db = 0; db < 4; ++db)
#pragma unroll
    for (int g = 0; g < 4; ++g) {
      us4 w4;
#pragma unroll
      for (int j = 0; j < 4; ++j) w4[j] = f2bf(oacc[db][g * 4 + j] * inv);
      const int s16 = (db * 4 + g) ^ (orow & 15);
      *(us4*)&Olds[orow * 128 + s16 * 8 + hi * 4] = w4;
    }
  __syncthreads();
#pragma unroll
  for (int x = 0; x < 8; ++x) {
    const int row = x * 8 + (tid >> 4);
    const int sl = tid & 15;
    us8 v = *(const us8*)&Olds[row * 128 + ((sl ^ (row & 15)) << 3)];
    *(us8*)(o + (size_t)(q0 + row) * HIDN + h * HDIM + sl * 8) = v;
  }
}

// ---------------------------------------------------------------- launch
extern "C" void kernel_launch(void* const* d_in, const int* in_sizes, int n_in,
                              void* d_out, int out_size, void* d_ws, size_t ws_size,
                              hipStream_t stream) {
  (void)in_sizes; (void)n_in; (void)out_size; (void)ws_size;
  const float* hidden = (const float*)d_in[0];
  const float* past_k = (const float*)d_in[3];
  const float* past_v = (const float*)d_in[4];
  const float* Wq = (const float*)d_in[5];
  const float* Wk = (const float*)d_in[6];
  const float* Wv = (const float*)d_in[7];
  const float* Wo = (const float*)d_in[8];
  float* out = (float*)d_out;

  char* w = (char*)d_ws;
  u16* hiddenb = (u16*)w; w += (size_t)QLEN * HIDN * 2;
  u16* wqkv    = (u16*)w; w += (size_t)NQKVC * HIDN * 2;
  u16* wo      = (u16*)w; w += (size_t)HIDN * HIDN * 2;
  u16* qkvraw  = (u16*)w; w += (size_t)QLEN * NQKVC * 2;
  u16* qrope   = (u16*)w; w += (size_t)QLEN * HIDN * 2;
  u16* kbuf    = (u16*)w; w += (size_t)NKVH * KVLEN * HDIM * 2;
  u16* vtbuf   = (u16*)w; w += (size_t)NKVH * HDIM * KVLEN * 2;
  u16* attnb   = (u16*)w; w += (size_t)QLEN * HIDN * 2;

  cvt_kernel<<<(QLEN * HIDN) / 1024, 256, 0, stream>>>(hidden, hiddenb, QLEN * HIDN);
  cvt_kernel<<<(NHEAD * HDIM * HIDN) / 1024, 256, 0, stream>>>(Wq, wqkv, NHEAD * HDIM * HIDN);
  cvt_kernel<<<(NKVH * HDIM * HIDN) / 1024, 256, 0, stream>>>(Wk, wqkv + (size_t)4096 * HIDN,
                                                              NKVH * HDIM * HIDN);
  cvt_kernel<<<(NKVH * HDIM * HIDN) / 1024, 256, 0, stream>>>(Wv, wqkv + (size_t)5120 * HIDN,
                                                              NKVH * HDIM * HIDN);
  cvt_kernel<<<(HIDN * HIDN) / 1024, 256, 0, stream>>>(Wo, wo, HIDN * HIDN);

  gemm_bt<u16><<<dim3(NQKVC / 128, QLEN / 128), 256, 0, stream>>>(hiddenb, wqkv, qkvraw,
                                                                  QLEN, NQKVC, HIDN);

  rope_q_kernel<<<(QLEN * NHEAD * 64) / 256, 256, 0, stream>>>(qkvraw, qrope);
  repack_k_kernel<<<(NKVH * KVLEN * HDIM) / 256, 256, 0, stream>>>(past_k, qkvraw, kbuf);
  repack_vt_kernel<<<dim3(KVLEN / 32, NKVH), 256, 0, stream>>>(past_v, qkvraw, vtbuf);

  attn_kernel<<<dim3(QLEN / 64, NHEAD), 128, 0, stream>>>(qrope, kbuf, vtbuf, attnb);

  gemm_bt<float><<<dim3(HIDN / 128, QLEN / 128), 256, 0, stream>>>(attnb, wo, out,
                                                                   QLEN, HIDN, HIDN);
}

// Round 5
// 381.902 us; speedup vs baseline: 1.0321x; 1.0321x over previous
//
#include <hip/hip_runtime.h>

#define QLEN 1024
#define PASTN 3072
#define KVLEN 4096
#define HIDN 4096
#define NHEAD 32
#define NKVH 8
#define HDIM 128
#define NQKVC 6144  // 4096 (Wq) + 1024 (Wk) + 1024 (Wv)

typedef unsigned short u16;
typedef __bf16 bf16x8 __attribute__((ext_vector_type(8)));
typedef float f32x4 __attribute__((ext_vector_type(4)));
typedef float f32x16 __attribute__((ext_vector_type(16)));
typedef u16 us8 __attribute__((ext_vector_type(8)));
typedef u16 us4 __attribute__((ext_vector_type(4)));

__device__ __forceinline__ u16 f2bf(float x) {
  unsigned u = __builtin_bit_cast(unsigned, x);
  u += 0x7fffu + ((u >> 16) & 1u);
  return (u16)(u >> 16);
}
__device__ __forceinline__ float bf2f(u16 b) {
  return __builtin_bit_cast(float, (unsigned)b << 16);
}

// async global->LDS, 16B per lane; LDS dest is wave-uniform base (+lane*16)
#define GLL16(gp, lp) __builtin_amdgcn_global_load_lds( \
    (const __attribute__((address_space(1))) void*)(gp), \
    (__attribute__((address_space(3))) void*)(lp), 16, 0, 0)

// ---------------------------------------------------------------- convert
__global__ __launch_bounds__(256) void cvt_kernel(const float* __restrict__ src,
                                                  u16* __restrict__ dst, int n) {
  int i = (blockIdx.x * 256 + threadIdx.x) * 4;
  if (i >= n) return;
  float4 f = *(const float4*)(src + i);
  ushort4 o = make_ushort4(f2bf(f.x), f2bf(f.y), f2bf(f.z), f2bf(f.w));
  *(ushort4*)(dst + i) = o;
}

// ---------------------------------------------------------------- GEMM C = A * B^T
// BM=64, BN=128, BK=32, 4 waves (each 32x64), dbuf LDS 24KB.
// LDS rows are 32 u16 (4 x 16B slots); slot XOR-swizzled by ((row>>1)&3) so
// fragment reads (16 rows, fixed slot) spread across all 8 bank-quads (2-way).
__device__ __forceinline__ void storeC(float* p, float v) { *p = v; }
__device__ __forceinline__ void storeC(u16* p, float v) { *p = f2bf(v); }

template <typename CT>
__global__ __launch_bounds__(256) void gemm_bt(const u16* __restrict__ A,
                                               const u16* __restrict__ B,
                                               CT* __restrict__ C, int M, int N, int K) {
  __shared__ u16 Alds[2][64 * 32];
  __shared__ u16 Blds[2][128 * 32];
  const int tid = threadIdx.x, wid = tid >> 6, lane = tid & 63;
  const int m0 = blockIdx.y * 64, n0 = blockIdx.x * 128;
  const int wm = (wid >> 1) * 32, wn = (wid & 1) * 64;
  const int l15 = lane & 15, l4 = lane >> 4;
  const int srow = lane >> 2, sp = lane & 3;
  f32x4 acc[2][4] = {};
  auto stage = [&](int buf, int kt) {
    {  // A: 4 chunks of 16 rows; wave w stages chunk w
      const int r = wid * 16 + srow;
      GLL16(A + (size_t)(m0 + r) * K + kt + (sp ^ ((r >> 1) & 3)) * 8,
            &Alds[buf][wid * 512]);
    }
#pragma unroll
    for (int i = 0; i < 2; ++i) {  // B: 8 chunks; wave w stages 2w, 2w+1
      const int c = wid * 2 + i;
      const int r = c * 16 + srow;
      GLL16(B + (size_t)(n0 + r) * K + kt + (sp ^ ((r >> 1) & 3)) * 8,
            &Blds[buf][c * 512]);
    }
  };
  stage(0, 0);
  __syncthreads();
  int cur = 0;
  for (int kt = 0; kt < K; kt += 32) {
    if (kt + 32 < K) stage(cur ^ 1, kt + 32);
    bf16x8 a[2], b[4];
#pragma unroll
    for (int i = 0; i < 2; ++i) {
      const int R = wm + i * 16 + l15;
      a[i] = *(const bf16x8*)&Alds[cur][R * 32 + (l4 ^ ((R >> 1) & 3)) * 8];
    }
#pragma unroll
    for (int j = 0; j < 4; ++j) {
      const int R = wn + j * 16 + l15;
      b[j] = *(const bf16x8*)&Blds[cur][R * 32 + (l4 ^ ((R >> 1) & 3)) * 8];
    }
#pragma unroll
    for (int i = 0; i < 2; ++i)
#pragma unroll
      for (int j = 0; j < 4; ++j)
        acc[i][j] = __builtin_amdgcn_mfma_f32_16x16x32_bf16(a[i], b[j], acc[i][j], 0, 0, 0);
    __syncthreads();
    cur ^= 1;
  }
#pragma unroll
  for (int i = 0; i < 2; ++i)
#pragma unroll
    for (int j = 0; j < 4; ++j) {
      int row = m0 + wm + i * 16 + l4 * 4;
      int col = n0 + wn + j * 16 + l15;
#pragma unroll
      for (int r = 0; r < 4; ++r) storeC(&C[(size_t)(row + r) * N + col], acc[i][j][r]);
    }
}

// ---------------------------------------------------------------- RoPE on Q
__global__ __launch_bounds__(256) void rope_q_kernel(const u16* __restrict__ qkv,
                                                     u16* __restrict__ qr) {
  int idx = blockIdx.x * 256 + threadIdx.x;  // 1024*32*64
  int i = idx & 63, h = (idx >> 6) & 31, r = idx >> 11;
  float freq = __expf(-(float)i * (9.210340371976184f / 64.f));
  float angle = (float)(PASTN + r) * freq;
  float sn, cs;
  sincosf(angle, &sn, &cs);
  int base = r * NQKVC + h * HDIM + i;
  float x1 = bf2f(qkv[base]);
  float x2 = bf2f(qkv[base + 64]);
  int ob = r * HIDN + h * HDIM + i;
  qr[ob] = f2bf(x1 * cs - x2 * sn);
  qr[ob + 64] = f2bf(x2 * cs + x1 * sn);
}

// ---------------------------------------------------------------- K cache build
__global__ __launch_bounds__(256) void repack_k_kernel(const float* __restrict__ past_k,
                                                       const u16* __restrict__ qkv,
                                                       u16* __restrict__ kb) {
  int idx = blockIdx.x * 256 + threadIdx.x;  // 8*4096*128
  int d = idx & 127, kv = (idx >> 7) & 4095, hk = idx >> 19;
  float val;
  if (kv < PASTN) {
    val = past_k[((size_t)hk * PASTN + kv) * HDIM + d];
  } else {
    int r = kv - PASTN;
    float x = bf2f(qkv[(size_t)r * NQKVC + 4096 + hk * HDIM + d]);
    float xp = bf2f(qkv[(size_t)r * NQKVC + 4096 + hk * HDIM + (d ^ 64)]);
    int i = d & 63;
    float freq = __expf(-(float)i * (9.210340371976184f / 64.f));
    float angle = (float)(PASTN + r) * freq;
    float sn, cs;
    sincosf(angle, &sn, &cs);
    val = (d < 64) ? (x * cs - xp * sn) : (x * cs + xp * sn);
  }
  kb[idx] = f2bf(val);
}

// ---------------------------------------------------------------- V^T cache build
__global__ __launch_bounds__(256) void repack_vt_kernel(const float* __restrict__ past_v,
                                                        const u16* __restrict__ qkv,
                                                        u16* __restrict__ vtb) {
  __shared__ u16 tile[32][136];
  int hk = blockIdx.y, kv0 = blockIdx.x * 32, tid = threadIdx.x;
  int j = tid >> 3, d0 = (tid & 7) * 16;
  if (kv0 < PASTN) {
    const float* src = past_v + ((size_t)hk * PASTN + kv0 + j) * HDIM + d0;
#pragma unroll
    for (int x = 0; x < 16; x += 4) {
      float4 f = *(const float4*)(src + x);
      tile[j][d0 + x] = f2bf(f.x);
      tile[j][d0 + x + 1] = f2bf(f.y);
      tile[j][d0 + x + 2] = f2bf(f.z);
      tile[j][d0 + x + 3] = f2bf(f.w);
    }
  } else {
    int r = kv0 - PASTN + j;
    const u16* src = qkv + (size_t)r * NQKVC + 5120 + hk * HDIM + d0;
    *(us8*)&tile[j][d0] = *(const us8*)src;
    *(us8*)&tile[j][d0 + 8] = *(const us8*)(src + 8);
  }
  __syncthreads();
  int d = tid >> 1, jb = (tid & 1) * 16;
  us8 o0, o1;
#pragma unroll
  for (int x = 0; x < 8; ++x) {
    o0[x] = tile[jb + x][d];
    o1[x] = tile[jb + 8 + x][d];
  }
  u16* dst = vtb + ((size_t)hk * HDIM + d) * KVLEN + kv0 + jb;
  *(us8*)dst = o0;
  *(us8*)(dst + 8) = o1;
}

// ---------------------------------------------------------------- flash attention
// 32x32x16 MFMA, swapped operands (S^T = mfma(K,Q), q = lane&31), K rows
// permuted by pi (swap bits 2<->3) so S^T regs are the PV B-fragment.
// Round 4: KV-split-2 (blockIdx.z) + SINGLE-buffer LDS (32KB) -> ~4 blocks/CU,
// 8 waves/CU; each block emits an unnormalized f32 partial (O, m, l).
__global__ __launch_bounds__(128) void attn_kernel(const u16* __restrict__ q,
                                                   const u16* __restrict__ kc,
                                                   const u16* __restrict__ vt,
                                                   float* __restrict__ opart,
                                                   float* __restrict__ mlbuf) {
  __shared__ u16 Klds[64 * 128];  // [row][d], swizzled, rows permuted by pi
  __shared__ u16 Vlds[128 * 64];  // [d][kv], swizzled
  const int tid = threadIdx.x, wid = tid >> 6, lane = tid & 63;
  const int l31 = lane & 31, hi = lane >> 5, l15 = lane & 15;
  const int h = blockIdx.y, hk = h >> 2;
  const int q0 = blockIdx.x * 64;
  const int z = blockIdx.z;
  const int pid = h * 16 + blockIdx.x;
  const int qrow = q0 + wid * 32 + l31;
  bf16x8 qf[8];
  {
    const u16* qp = q + (size_t)qrow * HIDN + h * HDIM + hi * 8;
#pragma unroll
    for (int dk = 0; dk < 8; ++dk) qf[dk] = *(const bf16x8*)(qp + dk * 16);
  }
  float m_run = -1e30f, l_run = 0.f;
  f32x16 oacc[4] = {};
  const u16* kbase = kc + (size_t)hk * KVLEN * HDIM;
  const u16* vbase = vt + (size_t)hk * HDIM * KVLEN;
  const int ntiles = (PASTN + q0 + 64) >> 6;
  const int half = ntiles >> 1;
  const int t0 = z ? half : 0, t1 = z ? ntiles : half;
  const float C = 0.12753102f;  // log2(e)/sqrt(128)
  const int qpos = PASTN + qrow;
  for (int t = t0; t < t1; ++t) {
    const int kv0 = t << 6;
    {  // K: 8 GLL/wave (4 phys rows each); V: 8 GLL/wave (8 d-rows each)
#pragma unroll
      for (int i = 0; i < 8; ++i) {
        const int w = wid * 8 + i;
        const int p = w * 4 + (lane >> 4);
        const int key = (p & 0x33) | ((p & 4) << 1) | ((p & 8) >> 1);
        const int sl = (lane & 15) ^ (p & 15);
        GLL16(kbase + (size_t)(kv0 + key) * HDIM + sl * 8, &Klds[w * 512]);
      }
#pragma unroll
      for (int i = 0; i < 8; ++i) {
        const int w = wid * 8 + i;
        const int d = w * 8 + (lane >> 3);
        const int sl = (lane & 7) ^ ((lane >> 3) & 7);
        GLL16(vbase + (size_t)d * KVLEN + kv0 + sl * 8, &Vlds[w * 512]);
      }
    }
    __syncthreads();
    // QK^T: s[tt] = S^T over keys kv0+32tt.., accumulated over 8 dk chunks
    f32x16 s[2] = {};
    __builtin_amdgcn_s_setprio(1);
#pragma unroll
    for (int tt = 0; tt < 2; ++tt)
#pragma unroll
      for (int dk = 0; dk < 8; ++dk) {
        const int idx = (tt * 32 + l31) * 128 + (((dk * 2 + hi) ^ l15) * 8);
        bf16x8 kf = *(const bf16x8*)&Klds[idx];
        s[tt] = __builtin_amdgcn_mfma_f32_32x32x16_bf16(kf, qf[dk], s[tt], 0, 0, 0);
      }
    __builtin_amdgcn_s_setprio(0);
    float pm = -1e30f;
    if (t == ntiles - 1) {
#pragma unroll
      for (int tt = 0; tt < 2; ++tt)
#pragma unroll
        for (int reg = 0; reg < 16; ++reg) {
          const int key = kv0 + tt * 32 + (reg & 7) + 8 * hi + ((reg & 8) << 1);
          float v = s[tt][reg] * C;
          if (key > qpos) v = -1e30f;
          s[tt][reg] = v;
          pm = fmaxf(pm, v);
        }
    } else {
#pragma unroll
      for (int tt = 0; tt < 2; ++tt)
#pragma unroll
        for (int reg = 0; reg < 16; ++reg) {
          float v = s[tt][reg] * C;
          s[tt][reg] = v;
          pm = fmaxf(pm, v);
        }
    }
    pm = fmaxf(pm, __shfl_xor(pm, 32));
    if (!__all(pm <= m_run)) {  // skip-rescale
      const float mn = fmaxf(m_run, pm);
      const float corr = exp2f(m_run - mn);
      m_run = mn;
      l_run *= corr;
#pragma unroll
      for (int db = 0; db < 4; ++db)
#pragma unroll
        for (int r = 0; r < 16; ++r) oacc[db][r] *= corr;
    }
    float rs = 0.f;
#pragma unroll
    for (int tt = 0; tt < 2; ++tt)
#pragma unroll
      for (int reg = 0; reg < 16; ++reg) {
        const float p = exp2f(s[tt][reg] - m_run);
        s[tt][reg] = p;
        rs += p;
      }
    rs += __shfl_xor(rs, 32);
    l_run += rs;
    // PV: O^T[d][q] += mfma(A=V^T frag, B=P-in-regs)
    __builtin_amdgcn_s_setprio(1);
#pragma unroll
    for (int kc2 = 0; kc2 < 4; ++kc2) {
      bf16x8 pa;
#pragma unroll
      for (int j = 0; j < 8; ++j) pa[j] = (__bf16)s[kc2 >> 1][(kc2 & 1) * 8 + j];
#pragma unroll
      for (int db = 0; db < 4; ++db) {
        const int idx = (db * 32 + l31) * 64 + (((kc2 * 2 + hi) ^ (l31 & 7)) * 8);
        bf16x8 vf = *(const bf16x8*)&Vlds[idx];
        oacc[db] = __builtin_amdgcn_mfma_f32_32x32x16_bf16(vf, pa, oacc[db], 0, 0, 0);
      }
    }
    __builtin_amdgcn_s_setprio(0);
    __syncthreads();
  }
  // epilogue: store unnormalized O^T partial ([q][d] f32) + per-row (m,l)
  const int orow = wid * 32 + l31;
  float* op = opart + (size_t)(z * 512 + pid) * (64 * 128) + orow * 128;
#pragma unroll
  for (int db = 0; db < 4; ++db)
#pragma unroll
    for (int g = 0; g < 4; ++g) {
      f32x4 w4;
#pragma unroll
      for (int j = 0; j < 4; ++j) w4[j] = oacc[db][g * 4 + j];
      *(f32x4*)&op[db * 32 + g * 8 + hi * 4] = w4;
    }
  if (hi == 0) {
    float* mlp = mlbuf + (size_t)((z * 512 + pid) * 64 + orow) * 2;
    mlp[0] = m_run;
    mlp[1] = l_run;
  }
}

// ---------------------------------------------------------------- combine partials
__global__ __launch_bounds__(256) void attn_combine(const float* __restrict__ opart,
                                                    const float* __restrict__ mlbuf,
                                                    u16* __restrict__ o) {
  const int pid = blockIdx.x;  // h*16 + qt
  const int h = pid >> 4, qt = pid & 15;
  const int q = threadIdx.x >> 2, dc = (threadIdx.x & 3) * 32;
  const float* ml0 = mlbuf + (size_t)(pid * 64 + q) * 2;
  const float* ml1 = mlbuf + (size_t)((512 + pid) * 64 + q) * 2;
  const float m0 = ml0[0], l0 = ml0[1], m1 = ml1[0], l1 = ml1[1];
  const float m = fmaxf(m0, m1);
  const float w0 = exp2f(m0 - m), w1 = exp2f(m1 - m);
  const float inv = 1.f / (w0 * l0 + w1 * l1);
  const float* O0 = opart + (size_t)pid * (64 * 128) + q * 128 + dc;
  const float* O1 = opart + (size_t)(512 + pid) * (64 * 128) + q * 128 + dc;
  u16* dst = o + (size_t)(qt * 64 + q) * HIDN + h * HDIM + dc;
#pragma unroll
  for (int x = 0; x < 8; ++x) {
    f32x4 a = *(const f32x4*)(O0 + x * 4);
    f32x4 b = *(const f32x4*)(O1 + x * 4);
    us4 w4;
#pragma unroll
    for (int j = 0; j < 4; ++j) w4[j] = f2bf((a[j] * w0 + b[j] * w1) * inv);
    *(us4*)(dst + x * 4) = w4;
  }
}

// ---------------------------------------------------------------- launch
extern "C" void kernel_launch(void* const* d_in, const int* in_sizes, int n_in,
                              void* d_out, int out_size, void* d_ws, size_t ws_size,
                              hipStream_t stream) {
  (void)in_sizes; (void)n_in; (void)out_size; (void)ws_size;
  const float* hidden = (const float*)d_in[0];
  const float* past_k = (const float*)d_in[3];
  const float* past_v = (const float*)d_in[4];
  const float* Wq = (const float*)d_in[5];
  const float* Wk = (const float*)d_in[6];
  const float* Wv = (const float*)d_in[7];
  const float* Wo = (const float*)d_in[8];
  float* out = (float*)d_out;

  char* w = (char*)d_ws;
  u16* hiddenb = (u16*)w; w += (size_t)QLEN * HIDN * 2;
  u16* wqkv    = (u16*)w; w += (size_t)NQKVC * HIDN * 2;   // 48MB; reused as opart/ml after GEMM1
  u16* wo      = (u16*)w; w += (size_t)HIDN * HIDN * 2;
  u16* qkvraw  = (u16*)w; w += (size_t)QLEN * NQKVC * 2;
  u16* qrope   = (u16*)w; w += (size_t)QLEN * HIDN * 2;
  u16* kbuf    = (u16*)w; w += (size_t)NKVH * KVLEN * HDIM * 2;
  u16* vtbuf   = (u16*)w; w += (size_t)NKVH * HDIM * KVLEN * 2;
  u16* attnb   = (u16*)w; w += (size_t)QLEN * HIDN * 2;
  // attn partials alias the (dead-after-GEMM1) wqkv region: 33.5MB + 0.5MB < 48MB
  float* opart = (float*)wqkv;
  float* mlbuf = opart + (size_t)2 * 512 * 64 * 128;

  cvt_kernel<<<(QLEN * HIDN) / 1024, 256, 0, stream>>>(hidden, hiddenb, QLEN * HIDN);
  cvt_kernel<<<(NHEAD * HDIM * HIDN) / 1024, 256, 0, stream>>>(Wq, wqkv, NHEAD * HDIM * HIDN);
  cvt_kernel<<<(NKVH * HDIM * HIDN) / 1024, 256, 0, stream>>>(Wk, wqkv + (size_t)4096 * HIDN,
                                                              NKVH * HDIM * HIDN);
  cvt_kernel<<<(NKVH * HDIM * HIDN) / 1024, 256, 0, stream>>>(Wv, wqkv + (size_t)5120 * HIDN,
                                                              NKVH * HDIM * HIDN);
  cvt_kernel<<<(HIDN * HIDN) / 1024, 256, 0, stream>>>(Wo, wo, HIDN * HIDN);

  gemm_bt<u16><<<dim3(NQKVC / 128, QLEN / 64), 256, 0, stream>>>(hiddenb, wqkv, qkvraw,
                                                                 QLEN, NQKVC, HIDN);

  rope_q_kernel<<<(QLEN * NHEAD * 64) / 256, 256, 0, stream>>>(qkvraw, qrope);
  repack_k_kernel<<<(NKVH * KVLEN * HDIM) / 256, 256, 0, stream>>>(past_k, qkvraw, kbuf);
  repack_vt_kernel<<<dim3(KVLEN / 32, NKVH), 256, 0, stream>>>(past_v, qkvraw, vtbuf);

  attn_kernel<<<dim3(QLEN / 64, NHEAD, 2), 128, 0, stream>>>(qrope, kbuf, vtbuf,
                                                             opart, mlbuf);
  attn_combine<<<512, 256, 0, stream>>>(opart, mlbuf, attnb);

  gemm_bt<float><<<dim3(HIDN / 128, QLEN / 64), 256, 0, stream>>>(attnb, wo, out,
                                                                  QLEN, HIDN, HIDN);
}

// Round 6
// 344.597 us; speedup vs baseline: 1.1439x; 1.1083x over previous
//
#include <hip/hip_runtime.h>

#define QLEN 1024
#define PASTN 3072
#define KVLEN 4096
#define HIDN 4096
#define NHEAD 32
#define NKVH 8
#define HDIM 128
#define NQKVC 6144  // 4096 (Wq) + 1024 (Wk) + 1024 (Wv)

typedef unsigned short u16;
typedef __bf16 bf16x8 __attribute__((ext_vector_type(8)));
typedef float f32x4 __attribute__((ext_vector_type(4)));
typedef float f32x16 __attribute__((ext_vector_type(16)));
typedef u16 us8 __attribute__((ext_vector_type(8)));
typedef u16 us4 __attribute__((ext_vector_type(4)));

__device__ __forceinline__ u16 f2bf(float x) {
  unsigned u = __builtin_bit_cast(unsigned, x);
  u += 0x7fffu + ((u >> 16) & 1u);
  return (u16)(u >> 16);
}
__device__ __forceinline__ float bf2f(u16 b) {
  return __builtin_bit_cast(float, (unsigned)b << 16);
}

// async global->LDS, 16B per lane; LDS dest is wave-uniform base (+lane*16)
#define GLL16(gp, lp) __builtin_amdgcn_global_load_lds( \
    (const __attribute__((address_space(1))) void*)(gp), \
    (__attribute__((address_space(3))) void*)(lp), 16, 0, 0)

// ---------------------------------------------------------------- convert
__global__ __launch_bounds__(256) void cvt_kernel(const float* __restrict__ src,
                                                  u16* __restrict__ dst, int n) {
  int i = (blockIdx.x * 256 + threadIdx.x) * 4;
  if (i >= n) return;
  float4 f = *(const float4*)(src + i);
  ushort4 o = make_ushort4(f2bf(f.x), f2bf(f.y), f2bf(f.z), f2bf(f.w));
  *(ushort4*)(dst + i) = o;
}

// ---------------------------------------------------------------- GEMM C = A * B^T
// BM=64, BN=128, BK=32, 4 waves (each 32x64), dbuf LDS 24KB (unchanged, R4).
__device__ __forceinline__ void storeC(float* p, float v) { *p = v; }
__device__ __forceinline__ void storeC(u16* p, float v) { *p = f2bf(v); }

template <typename CT>
__global__ __launch_bounds__(256) void gemm_bt(const u16* __restrict__ A,
                                               const u16* __restrict__ B,
                                               CT* __restrict__ C, int M, int N, int K) {
  __shared__ u16 Alds[2][64 * 32];
  __shared__ u16 Blds[2][128 * 32];
  const int tid = threadIdx.x, wid = tid >> 6, lane = tid & 63;
  const int m0 = blockIdx.y * 64, n0 = blockIdx.x * 128;
  const int wm = (wid >> 1) * 32, wn = (wid & 1) * 64;
  const int l15 = lane & 15, l4 = lane >> 4;
  const int srow = lane >> 2, sp = lane & 3;
  f32x4 acc[2][4] = {};
  auto stage = [&](int buf, int kt) {
    {
      const int r = wid * 16 + srow;
      GLL16(A + (size_t)(m0 + r) * K + kt + (sp ^ ((r >> 1) & 3)) * 8,
            &Alds[buf][wid * 512]);
    }
#pragma unroll
    for (int i = 0; i < 2; ++i) {
      const int c = wid * 2 + i;
      const int r = c * 16 + srow;
      GLL16(B + (size_t)(n0 + r) * K + kt + (sp ^ ((r >> 1) & 3)) * 8,
            &Blds[buf][c * 512]);
    }
  };
  stage(0, 0);
  __syncthreads();
  int cur = 0;
  for (int kt = 0; kt < K; kt += 32) {
    if (kt + 32 < K) stage(cur ^ 1, kt + 32);
    bf16x8 a[2], b[4];
#pragma unroll
    for (int i = 0; i < 2; ++i) {
      const int R = wm + i * 16 + l15;
      a[i] = *(const bf16x8*)&Alds[cur][R * 32 + (l4 ^ ((R >> 1) & 3)) * 8];
    }
#pragma unroll
    for (int j = 0; j < 4; ++j) {
      const int R = wn + j * 16 + l15;
      b[j] = *(const bf16x8*)&Blds[cur][R * 32 + (l4 ^ ((R >> 1) & 3)) * 8];
    }
#pragma unroll
    for (int i = 0; i < 2; ++i)
#pragma unroll
      for (int j = 0; j < 4; ++j)
        acc[i][j] = __builtin_amdgcn_mfma_f32_16x16x32_bf16(a[i], b[j], acc[i][j], 0, 0, 0);
    __syncthreads();
    cur ^= 1;
  }
#pragma unroll
  for (int i = 0; i < 2; ++i)
#pragma unroll
    for (int j = 0; j < 4; ++j) {
      int row = m0 + wm + i * 16 + l4 * 4;
      int col = n0 + wn + j * 16 + l15;
#pragma unroll
      for (int r = 0; r < 4; ++r) storeC(&C[(size_t)(row + r) * N + col], acc[i][j][r]);
    }
}

// ---------------------------------------------------------------- RoPE on Q
__global__ __launch_bounds__(256) void rope_q_kernel(const u16* __restrict__ qkv,
                                                     u16* __restrict__ qr) {
  int idx = blockIdx.x * 256 + threadIdx.x;  // 1024*32*64
  int i = idx & 63, h = (idx >> 6) & 31, r = idx >> 11;
  float freq = __expf(-(float)i * (9.210340371976184f / 64.f));
  float angle = (float)(PASTN + r) * freq;
  float sn, cs;
  sincosf(angle, &sn, &cs);
  int base = r * NQKVC + h * HDIM + i;
  float x1 = bf2f(qkv[base]);
  float x2 = bf2f(qkv[base + 64]);
  int ob = r * HIDN + h * HDIM + i;
  qr[ob] = f2bf(x1 * cs - x2 * sn);
  qr[ob + 64] = f2bf(x2 * cs + x1 * sn);
}

// ---------------------------------------------------------------- K cache build
__global__ __launch_bounds__(256) void repack_k_kernel(const float* __restrict__ past_k,
                                                       const u16* __restrict__ qkv,
                                                       u16* __restrict__ kb) {
  int idx = blockIdx.x * 256 + threadIdx.x;  // 8*4096*128
  int d = idx & 127, kv = (idx >> 7) & 4095, hk = idx >> 19;
  float val;
  if (kv < PASTN) {
    val = past_k[((size_t)hk * PASTN + kv) * HDIM + d];
  } else {
    int r = kv - PASTN;
    float x = bf2f(qkv[(size_t)r * NQKVC + 4096 + hk * HDIM + d]);
    float xp = bf2f(qkv[(size_t)r * NQKVC + 4096 + hk * HDIM + (d ^ 64)]);
    int i = d & 63;
    float freq = __expf(-(float)i * (9.210340371976184f / 64.f));
    float angle = (float)(PASTN + r) * freq;
    float sn, cs;
    sincosf(angle, &sn, &cs);
    val = (d < 64) ? (x * cs - xp * sn) : (x * cs + xp * sn);
  }
  kb[idx] = f2bf(val);
}

// ---------------------------------------------------------------- V^T cache build
__global__ __launch_bounds__(256) void repack_vt_kernel(const float* __restrict__ past_v,
                                                        const u16* __restrict__ qkv,
                                                        u16* __restrict__ vtb) {
  __shared__ u16 tile[32][136];
  int hk = blockIdx.y, kv0 = blockIdx.x * 32, tid = threadIdx.x;
  int j = tid >> 3, d0 = (tid & 7) * 16;
  if (kv0 < PASTN) {
    const float* src = past_v + ((size_t)hk * PASTN + kv0 + j) * HDIM + d0;
#pragma unroll
    for (int x = 0; x < 16; x += 4) {
      float4 f = *(const float4*)(src + x);
      tile[j][d0 + x] = f2bf(f.x);
      tile[j][d0 + x + 1] = f2bf(f.y);
      tile[j][d0 + x + 2] = f2bf(f.z);
      tile[j][d0 + x + 3] = f2bf(f.w);
    }
  } else {
    int r = kv0 - PASTN + j;
    const u16* src = qkv + (size_t)r * NQKVC + 5120 + hk * HDIM + d0;
    *(us8*)&tile[j][d0] = *(const us8*)src;
    *(us8*)&tile[j][d0 + 8] = *(const us8*)(src + 8);
  }
  __syncthreads();
  int d = tid >> 1, jb = (tid & 1) * 16;
  us8 o0, o1;
#pragma unroll
  for (int x = 0; x < 8; ++x) {
    o0[x] = tile[jb + x][d];
    o1[x] = tile[jb + 8 + x][d];
  }
  u16* dst = vtb + ((size_t)hk * HDIM + d) * KVLEN + kv0 + jb;
  *(us8*)dst = o0;
  *(us8*)(dst + 8) = o1;
}

// ---------------------------------------------------------------- flash attention
// 32x32x16 MFMA, swapped operands (S^T = mfma(K,Q), q = lane&31), K rows
// permuted by pi (swap bits 2<->3) so S^T regs are the PV B-fragment.
// Round 5: 8-wave (512-thr) blocks, q-tile 256 (wave = 32 q), shared KV tile
// of 64 staged by all 8 waves (4 GLL/wave), dbuf LDS 64KB, z-split-2.
__global__ __launch_bounds__(512) void attn_kernel(const u16* __restrict__ q,
                                                   const u16* __restrict__ kc,
                                                   const u16* __restrict__ vt,
                                                   float* __restrict__ opart,
                                                   float* __restrict__ mlbuf) {
  __shared__ u16 Klds[2][64 * 128];  // [row][d], swizzled, rows permuted by pi
  __shared__ u16 Vlds[2][128 * 64];  // [d][kv], swizzled
  const int tid = threadIdx.x, wid = tid >> 6, lane = tid & 63;
  const int l31 = lane & 31, hi = lane >> 5, l15 = lane & 15;
  const int h = blockIdx.y, hk = h >> 2;
  const int q0 = blockIdx.x * 256;
  const int z = blockIdx.z;
  const int pid = h * 4 + blockIdx.x;
  const int qrow = q0 + wid * 32 + l31;
  bf16x8 qf[8];
  {
    const u16* qp = q + (size_t)qrow * HIDN + h * HDIM + hi * 8;
#pragma unroll
    for (int dk = 0; dk < 8; ++dk) qf[dk] = *(const bf16x8*)(qp + dk * 16);
  }
  float m_run = -1e30f, l_run = 0.f;
  f32x16 oacc[4] = {};
  const u16* kbase = kc + (size_t)hk * KVLEN * HDIM;
  const u16* vbase = vt + (size_t)hk * HDIM * KVLEN;
  const int ntiles = (PASTN + q0 + 256) >> 6;
  const int half = ntiles >> 1;
  const int t0 = z ? half : 0, t1 = z ? ntiles : half;
  const float C = 0.12753102f;  // log2(e)/sqrt(128)
  const int qpos = PASTN + qrow;
  auto stage = [&](int buf, int kv0) {
    // K: 16 chunks of 1KB (4 phys rows each); wave w stages chunks 2w, 2w+1
#pragma unroll
    for (int i = 0; i < 2; ++i) {
      const int w = wid * 2 + i;
      const int p = w * 4 + (lane >> 4);
      const int key = (p & 0x33) | ((p & 4) << 1) | ((p & 8) >> 1);
      const int sl = (lane & 15) ^ (p & 15);
      GLL16(kbase + (size_t)(kv0 + key) * HDIM + sl * 8, &Klds[buf][w * 512]);
    }
    // V: 16 chunks of 1KB (8 d-rows each)
#pragma unroll
    for (int i = 0; i < 2; ++i) {
      const int w = wid * 2 + i;
      const int d = w * 8 + (lane >> 3);
      const int sl = (lane & 7) ^ ((lane >> 3) & 7);
      GLL16(vbase + (size_t)d * KVLEN + kv0 + sl * 8, &Vlds[buf][w * 512]);
    }
  };
  stage(0, t0 << 6);
  __syncthreads();
  int cur = 0;
  for (int t = t0; t < t1; ++t) {
    if (t + 1 < t1) stage(cur ^ 1, (t + 1) << 6);
    const int kv0 = t << 6;
    const u16* Kb = Klds[cur];
    const u16* Vb = Vlds[cur];
    // QK^T: s[tt] = S^T over keys kv0+32tt.., accumulated over 8 dk chunks
    f32x16 s[2] = {};
    __builtin_amdgcn_s_setprio(1);
#pragma unroll
    for (int tt = 0; tt < 2; ++tt)
#pragma unroll
      for (int dk = 0; dk < 8; ++dk) {
        const int idx = (tt * 32 + l31) * 128 + (((dk * 2 + hi) ^ l15) * 8);
        bf16x8 kf = *(const bf16x8*)&Kb[idx];
        s[tt] = __builtin_amdgcn_mfma_f32_32x32x16_bf16(kf, qf[dk], s[tt], 0, 0, 0);
      }
    __builtin_amdgcn_s_setprio(0);
    float pm = -1e30f;
    if (kv0 + 63 > PASTN + q0) {  // any masked key in this tile (for some wave)
#pragma unroll
      for (int tt = 0; tt < 2; ++tt)
#pragma unroll
        for (int reg = 0; reg < 16; ++reg) {
          const int key = kv0 + tt * 32 + (reg & 7) + 8 * hi + ((reg & 8) << 1);
          float v = s[tt][reg] * C;
          if (key > qpos) v = -1e30f;
          s[tt][reg] = v;
          pm = fmaxf(pm, v);
        }
    } else {
#pragma unroll
      for (int tt = 0; tt < 2; ++tt)
#pragma unroll
        for (int reg = 0; reg < 16; ++reg) {
          float v = s[tt][reg] * C;
          s[tt][reg] = v;
          pm = fmaxf(pm, v);
        }
    }
    pm = fmaxf(pm, __shfl_xor(pm, 32));
    if (!__all(pm <= m_run)) {  // skip-rescale
      const float mn = fmaxf(m_run, pm);
      const float corr = exp2f(m_run - mn);
      m_run = mn;
      l_run *= corr;
#pragma unroll
      for (int db = 0; db < 4; ++db)
#pragma unroll
        for (int r = 0; r < 16; ++r) oacc[db][r] *= corr;
    }
    float rs = 0.f;
#pragma unroll
    for (int tt = 0; tt < 2; ++tt)
#pragma unroll
      for (int reg = 0; reg < 16; ++reg) {
        const float p = exp2f(s[tt][reg] - m_run);
        s[tt][reg] = p;
        rs += p;
      }
    rs += __shfl_xor(rs, 32);
    l_run += rs;
    // PV: O^T[d][q] += mfma(A=V^T frag, B=P-in-regs)
    __builtin_amdgcn_s_setprio(1);
#pragma unroll
    for (int kc2 = 0; kc2 < 4; ++kc2) {
      bf16x8 pa;
#pragma unroll
      for (int j = 0; j < 8; ++j) pa[j] = (__bf16)s[kc2 >> 1][(kc2 & 1) * 8 + j];
#pragma unroll
      for (int db = 0; db < 4; ++db) {
        const int idx = (db * 32 + l31) * 64 + (((kc2 * 2 + hi) ^ (l31 & 7)) * 8);
        bf16x8 vf = *(const bf16x8*)&Vb[idx];
        oacc[db] = __builtin_amdgcn_mfma_f32_32x32x16_bf16(vf, pa, oacc[db], 0, 0, 0);
      }
    }
    __builtin_amdgcn_s_setprio(0);
    __syncthreads();
    cur ^= 1;
  }
  // epilogue: store unnormalized O^T partial ([q][d] f32) + per-row (m,l)
  const int orow = wid * 32 + l31;
  float* op = opart + ((size_t)(z * 128 + pid) * 256 + orow) * 128;
#pragma unroll
  for (int db = 0; db < 4; ++db)
#pragma unroll
    for (int g = 0; g < 4; ++g) {
      f32x4 w4;
#pragma unroll
      for (int j = 0; j < 4; ++j) w4[j] = oacc[db][g * 4 + j];
      *(f32x4*)&op[db * 32 + g * 8 + hi * 4] = w4;
    }
  if (hi == 0) {
    float* mlp = mlbuf + ((size_t)(z * 128 + pid) * 256 + orow) * 2;
    mlp[0] = m_run;
    mlp[1] = l_run;
  }
}

// ---------------------------------------------------------------- combine partials
__global__ __launch_bounds__(256) void attn_combine(const float* __restrict__ opart,
                                                    const float* __restrict__ mlbuf,
                                                    u16* __restrict__ o) {
  const int pid = blockIdx.x;  // h*4 + qt
  const int h = pid >> 2, qt = pid & 3;
  const int q2 = threadIdx.x >> 2, dc = (threadIdx.x & 3) * 32;
#pragma unroll
  for (int b = 0; b < 4; ++b) {
    const int q = b * 64 + q2;
    const float* ml0 = mlbuf + ((size_t)pid * 256 + q) * 2;
    const float* ml1 = mlbuf + ((size_t)(128 + pid) * 256 + q) * 2;
    const float m0 = ml0[0], l0 = ml0[1], m1 = ml1[0], l1 = ml1[1];
    const float m = fmaxf(m0, m1);
    const float w0 = exp2f(m0 - m), w1 = exp2f(m1 - m);
    const float inv = 1.f / (w0 * l0 + w1 * l1);
    const float* O0 = opart + ((size_t)pid * 256 + q) * 128 + dc;
    const float* O1 = opart + ((size_t)(128 + pid) * 256 + q) * 128 + dc;
    u16* dst = o + (size_t)(qt * 256 + q) * HIDN + h * HDIM + dc;
#pragma unroll
    for (int x = 0; x < 8; ++x) {
      f32x4 a = *(const f32x4*)(O0 + x * 4);
      f32x4 bb = *(const f32x4*)(O1 + x * 4);
      us4 w4;
#pragma unroll
      for (int j = 0; j < 4; ++j) w4[j] = f2bf((a[j] * w0 + bb[j] * w1) * inv);
      *(us4*)(dst + x * 4) = w4;
    }
  }
}

// ---------------------------------------------------------------- launch
extern "C" void kernel_launch(void* const* d_in, const int* in_sizes, int n_in,
                              void* d_out, int out_size, void* d_ws, size_t ws_size,
                              hipStream_t stream) {
  (void)in_sizes; (void)n_in; (void)out_size; (void)ws_size;
  const float* hidden = (const float*)d_in[0];
  const float* past_k = (const float*)d_in[3];
  const float* past_v = (const float*)d_in[4];
  const float* Wq = (const float*)d_in[5];
  const float* Wk = (const float*)d_in[6];
  const float* Wv = (const float*)d_in[7];
  const float* Wo = (const float*)d_in[8];
  float* out = (float*)d_out;

  char* w = (char*)d_ws;
  u16* hiddenb = (u16*)w; w += (size_t)QLEN * HIDN * 2;
  u16* wqkv    = (u16*)w; w += (size_t)NQKVC * HIDN * 2;   // 48MB; reused as opart/ml after GEMM1
  u16* wo      = (u16*)w; w += (size_t)HIDN * HIDN * 2;
  u16* qkvraw  = (u16*)w; w += (size_t)QLEN * NQKVC * 2;
  u16* qrope   = (u16*)w; w += (size_t)QLEN * HIDN * 2;
  u16* kbuf    = (u16*)w; w += (size_t)NKVH * KVLEN * HDIM * 2;
  u16* vtbuf   = (u16*)w; w += (size_t)NKVH * HDIM * KVLEN * 2;
  u16* attnb   = (u16*)w; w += (size_t)QLEN * HIDN * 2;
  // attn partials alias the (dead-after-GEMM1) wqkv region: 33.5MB + 0.5MB < 48MB
  float* opart = (float*)wqkv;
  float* mlbuf = opart + (size_t)2 * 128 * 256 * 128;

  cvt_kernel<<<(QLEN * HIDN) / 1024, 256, 0, stream>>>(hidden, hiddenb, QLEN * HIDN);
  cvt_kernel<<<(NHEAD * HDIM * HIDN) / 1024, 256, 0, stream>>>(Wq, wqkv, NHEAD * HDIM * HIDN);
  cvt_kernel<<<(NKVH * HDIM * HIDN) / 1024, 256, 0, stream>>>(Wk, wqkv + (size_t)4096 * HIDN,
                                                              NKVH * HDIM * HIDN);
  cvt_kernel<<<(NKVH * HDIM * HIDN) / 1024, 256, 0, stream>>>(Wv, wqkv + (size_t)5120 * HIDN,
                                                              NKVH * HDIM * HIDN);
  cvt_kernel<<<(HIDN * HIDN) / 1024, 256, 0, stream>>>(Wo, wo, HIDN * HIDN);

  gemm_bt<u16><<<dim3(NQKVC / 128, QLEN / 64), 256, 0, stream>>>(hiddenb, wqkv, qkvraw,
                                                                 QLEN, NQKVC, HIDN);

  rope_q_kernel<<<(QLEN * NHEAD * 64) / 256, 256, 0, stream>>>(qkvraw, qrope);
  repack_k_kernel<<<(NKVH * KVLEN * HDIM) / 256, 256, 0, stream>>>(past_k, qkvraw, kbuf);
  repack_vt_kernel<<<dim3(KVLEN / 32, NKVH), 256, 0, stream>>>(past_v, qkvraw, vtbuf);

  attn_kernel<<<dim3(QLEN / 256, NHEAD, 2), 512, 0, stream>>>(qrope, kbuf, vtbuf,
                                                              opart, mlbuf);
  attn_combine<<<128, 256, 0, stream>>>(opart, mlbuf, attnb);

  gemm_bt<float><<<dim3(HIDN / 128, QLEN / 64), 256, 0, stream>>>(attnb, wo, out,
                                                                  QLEN, HIDN, HIDN);
}